// Round 8
// baseline (227.762 us; speedup 1.0000x reference)
//
#include <hip/hip_runtime.h>
#include <hip/hip_bf16.h>
#include <stdint.h>

// MLP: hidden = X @ W1^T + b1 ; out = hidden @ W2^T + b2
// X [16384,2048] f32, W1 [512,2048], b1 [512], W2 [2048,512], b2 [2048]
// R11: R10's A/B: a literal gemm2 clone (same structure+dtype) still runs
// 2x gemm2's per-byte rate -> remaining diff is grid 512 (2 blocks/CU,
// grid-limited; time = NSTEP x L regardless of tile, explaining R8's null)
// vs gemm2's 2048-block queue at the LDS cap of 5 blocks/CU.
// Fix: split-K=4 gemm1 -> 2048 blocks x 8 steps (gemm2's exact operating
// point), f32 unsafeAtomicAdd (native global_atomic_add_f32, device scope)
// into zeroed Hf; bias+bf16-cast in a small combine pass. Hf zeroing fused
// into the cast kernel. gemm2 unchanged (control).

typedef short bf16x8 __attribute__((ext_vector_type(8)));
typedef float f32x4 __attribute__((ext_vector_type(4)));

static __device__ __forceinline__ unsigned short f32_to_bf16_rne(float f) {
    unsigned int u = __float_as_uint(f);
    u += 0x7fffu + ((u >> 16) & 1u);
    return (unsigned short)(u >> 16);
}

// one streaming kernel: cast X, W1, W2 f32->bf16 AND zero Hf (write-only)
__global__ void cast_zero(const float* __restrict__ x,
                          unsigned short* __restrict__ xo, int nx4,
                          const float* __restrict__ w1,
                          unsigned short* __restrict__ w1o,
                          const float* __restrict__ w2,
                          unsigned short* __restrict__ w2o, int nw4,
                          float* __restrict__ hf, int nh4) {
    const int total = nx4 + 2 * nw4 + nh4;
    const int stride = gridDim.x * blockDim.x;
    for (int i = blockIdx.x * blockDim.x + threadIdx.x; i < total; i += stride) {
        if (i >= nx4 + 2 * nw4) {               // Hf zero segment
            float4 z = {0.f, 0.f, 0.f, 0.f};
            ((float4*)hf)[i - nx4 - 2 * nw4] = z;
            continue;
        }
        const float* in;
        unsigned short* out;
        int j;
        if (i < nx4) {
            in = x; out = xo; j = i;
        } else if (i < nx4 + nw4) {
            in = w1; out = w1o; j = i - nx4;
        } else {
            in = w2; out = w2o; j = i - nx4 - nw4;
        }
        float4 v = ((const float4*)in)[j];
        ushort4 o;
        o.x = f32_to_bf16_rne(v.x);
        o.y = f32_to_bf16_rne(v.y);
        o.z = f32_to_bf16_rne(v.z);
        o.w = f32_to_bf16_rne(v.w);
        ((ushort4*)out)[j] = o;
    }
}

// Hbf = bf16(Hf + b1) : combine split-K partial sums with bias
__global__ void combineH(const float* __restrict__ Hf,
                         const float* __restrict__ b1,
                         unsigned short* __restrict__ Hbf, int n4) {
    const int stride = gridDim.x * blockDim.x;
    for (int i = blockIdx.x * blockDim.x + threadIdx.x; i < n4; i += stride) {
        float4 v = ((const float4*)Hf)[i];
        const int c = (i << 2) & 511;            // col of first elem (x4 align)
        float4 bb = *(const float4*)(b1 + c);
        ushort4 o;
        o.x = f32_to_bf16_rne(v.x + bb.x);
        o.y = f32_to_bf16_rne(v.y + bb.y);
        o.z = f32_to_bf16_rne(v.z + bb.z);
        o.w = f32_to_bf16_rne(v.w + bb.w);
        ((ushort4*)Hbf)[i] = o;
    }
}

#define GLOAD_LDS16(gsrc, ldst)                                              \
    __builtin_amdgcn_global_load_lds(                                        \
        (const __attribute__((address_space(1))) void*)(gsrc),               \
        (__attribute__((address_space(3))) void*)(ldst), 16, 0, 0)

// ---------------------------------------------------------------------------
// GEMM1 split-K=4: Hf[16384][512] f32 += Xbf[16384][2048] @ W1bf^T  (chunk kv)
// 128x128 tile, 256 thr (2x2 waves of 64x64), BK=64, K-chunk = 512 -> 8 steps.
// grid = 4 x 512 = 2048 blocks -> LDS-capped 5 blocks/CU queue (gemm2's
// operating point). Chunked XCD swizzle q=256: each XCD gets half a kv-plane
// (fixed kv, 4 col-panels of each row-panel adjacent -> A-panel L2 reuse).
// Epilogue: f32 unsafeAtomicAdd into Hf (device-scope, cross-XCD safe).
// ---------------------------------------------------------------------------
__global__ __launch_bounds__(256)
void gemm1_splitk(const unsigned short* __restrict__ A,
                  const unsigned short* __restrict__ Bt,
                  float* __restrict__ Hf) {
    constexpr int N = 512, K = 2048, BK = 64, KSPLIT = 512;
    constexpr int NSTEP = KSPLIT / BK;  // 8 steps

    __shared__ __align__(16) unsigned short ldsA[128 * BK];  // 16 KB
    __shared__ __align__(16) unsigned short ldsB[128 * BK];  // 16 KB

    const int tid  = threadIdx.x;
    const int lane = tid & 63;
    const int wid  = tid >> 6;
    const int wr   = wid >> 1;
    const int wc   = wid & 1;

    const int bid = blockIdx.x;
    const int swz = ((bid & 7) << 8) + (bid >> 3);   // nwg=2048, q=256
    const int kv   = swz >> 9;                       // 0..3 K-chunk
    const int tile = swz & 511;
    const int bm  = tile >> 2;                       // 0..127 row-panel
    const int bn  = tile & 3;                        // 0..3 col-panel
    const int brow = bm << 7;
    const int bcol = bn << 7;
    const int kbase = kv * KSPLIT;

    const int lrow = lane & 15;
    const int ku   = lane >> 4;
    const int rx   = lrow & 7;

    const int srow = tid >> 3;
    const int sgu  = (tid & 7) ^ (srow & 7);

    f32x4 acc[4][4] = {};

    auto stage = [&](int k0) {
#pragma unroll
        for (int i = 0; i < 4; ++i) {
            const int row = i * 32 + srow;
            const char* sa =
                (const char*)(A + (size_t)(brow + row) * K + k0) + (sgu << 4);
            const char* sb =
                (const char*)(Bt + (size_t)(bcol + row) * K + k0) + (sgu << 4);
            GLOAD_LDS16(sa, (char*)ldsA + i * 4096 + tid * 16);
            GLOAD_LDS16(sb, (char*)ldsB + i * 4096 + tid * 16);
        }
    };
    auto compute = [&]() {
#pragma unroll
        for (int kk = 0; kk < 2; ++kk) {
            const int un = ((ku + (kk << 2)) ^ rx) << 4;
            bf16x8 a[4], b[4];
#pragma unroll
            for (int m = 0; m < 4; ++m)
                a[m] = *(const bf16x8*)((const char*)ldsA +
                       ((wr << 6) + (m << 4) + lrow) * 128 + un);
#pragma unroll
            for (int n = 0; n < 4; ++n)
                b[n] = *(const bf16x8*)((const char*)ldsB +
                       ((wc << 6) + (n << 4) + lrow) * 128 + un);
#pragma unroll
            for (int m = 0; m < 4; ++m)
#pragma unroll
                for (int n = 0; n < 4; ++n)
                    acc[m][n] = __builtin_amdgcn_mfma_f32_16x16x32_bf16(
                        a[m], b[n], acc[m][n], 0, 0, 0);
        }
    };

    stage(kbase);
    __syncthreads();

#pragma unroll 1
    for (int t = 0; t < NSTEP; ++t) {
        compute();
        if (t + 1 < NSTEP) {
            __syncthreads();
            stage(kbase + (t + 1) * BK);
            __syncthreads();
        }
    }

    // epilogue: C/D layout col = lane&15, row = (lane>>4)*4 + j  [m89]
    // f32 atomic add into Hf (native global_atomic_add_f32 via unsafeAtomicAdd)
    const int r0 = (lane >> 4) << 2;
#pragma unroll
    for (int n = 0; n < 4; ++n) {
        const int col = bcol + (wc << 6) + (n << 4) + lrow;
#pragma unroll
        for (int m = 0; m < 4; ++m)
#pragma unroll
            for (int j = 0; j < 4; ++j) {
                const int row = brow + (wr << 6) + (m << 4) + r0 + j;
                unsafeAtomicAdd(&Hf[(size_t)row * N + col], acc[m][n][j]);
            }
    }
}

// ---------------------------------------------------------------------------
// GEMM2: out[16384][2048] f32 = Hbf[16384][512] @ W2bf[2048][512]^T + b2
// 128x128 tile, 256 thr, BK=64, single-buffered 32 KB -> 5 blocks/CU.
// grid = 128*16 = 2048 blocks, chunked XCD swizzle (q=256). (unchanged)
// ---------------------------------------------------------------------------
__global__ __launch_bounds__(256)
void gemm2(const unsigned short* __restrict__ A,
           const unsigned short* __restrict__ Bt,
           const float* __restrict__ bias,
           float* __restrict__ C) {
    constexpr int N = 2048, Kd = 512, BK = 64, NSTEP = Kd / BK;  // 8 steps

    __shared__ __align__(16) unsigned short ldsA[128 * BK];  // 16 KB
    __shared__ __align__(16) unsigned short ldsB[128 * BK];  // 16 KB

    const int tid  = threadIdx.x;
    const int lane = tid & 63;
    const int wid  = tid >> 6;
    const int wr   = wid >> 1;
    const int wc   = wid & 1;

    const int bid = blockIdx.x;
    const int swz = ((bid & 7) << 8) + (bid >> 3);   // nwg=2048, q=256
    const int bn  = swz & 15;
    const int bm  = swz >> 4;
    const int brow = bm << 7;
    const int bcol = bn << 7;

    const int lrow = lane & 15;
    const int ku   = lane >> 4;
    const int rx   = lrow & 7;

    const int srow = tid >> 3;
    const int sgu  = (tid & 7) ^ (srow & 7);

    f32x4 acc[4][4] = {};

    auto stage = [&](int k0) {
#pragma unroll
        for (int i = 0; i < 4; ++i) {
            const int row = i * 32 + srow;
            const char* sa =
                (const char*)(A + (size_t)(brow + row) * Kd + k0) + (sgu << 4);
            const char* sb =
                (const char*)(Bt + (size_t)(bcol + row) * Kd + k0) + (sgu << 4);
            GLOAD_LDS16(sa, (char*)ldsA + i * 4096 + tid * 16);
            GLOAD_LDS16(sb, (char*)ldsB + i * 4096 + tid * 16);
        }
    };
    auto compute = [&]() {
#pragma unroll
        for (int kk = 0; kk < 2; ++kk) {
            const int un = ((ku + (kk << 2)) ^ rx) << 4;
            bf16x8 a[4], b[4];
#pragma unroll
            for (int m = 0; m < 4; ++m)
                a[m] = *(const bf16x8*)((const char*)ldsA +
                       ((wr << 6) + (m << 4) + lrow) * 128 + un);
#pragma unroll
            for (int n = 0; n < 4; ++n)
                b[n] = *(const bf16x8*)((const char*)ldsB +
                       ((wc << 6) + (n << 4) + lrow) * 128 + un);
#pragma unroll
            for (int m = 0; m < 4; ++m)
#pragma unroll
                for (int n = 0; n < 4; ++n)
                    acc[m][n] = __builtin_amdgcn_mfma_f32_16x16x32_bf16(
                        a[m], b[n], acc[m][n], 0, 0, 0);
        }
    };

    stage(0);
    __syncthreads();

    for (int t = 0; t < NSTEP; ++t) {
        compute();
        if (t + 1 < NSTEP) {
            __syncthreads();
            stage((t + 1) * BK);
            __syncthreads();
        }
    }

    const int r0 = (lane >> 4) << 2;
#pragma unroll
    for (int n = 0; n < 4; ++n) {
        const int col = bcol + (wc << 6) + (n << 4) + lrow;
        const float bb = bias[col];
#pragma unroll
        for (int m = 0; m < 4; ++m)
#pragma unroll
            for (int j = 0; j < 4; ++j) {
                const int row = brow + (wr << 6) + (m << 4) + r0 + j;
                C[(size_t)row * N + col] = acc[m][n][j] + bb;
            }
    }
}

extern "C" void kernel_launch(void* const* d_in, const int* in_sizes, int n_in,
                              void* d_out, int out_size, void* d_ws, size_t ws_size,
                              hipStream_t stream) {
    const float* X  = (const float*)d_in[0];   // [16384][2048]
    const float* W1 = (const float*)d_in[1];   // [512][2048]
    const float* b1 = (const float*)d_in[2];   // [512]
    const float* W2 = (const float*)d_in[3];   // [2048][512]
    const float* b2 = (const float*)d_in[4];   // [2048]

    const int B = 16384, M = 2048, Kd = 512;

    // workspace: W1bf (2MB), W2bf (2MB), Hbf (16.8MB), Xbf (64MB), Hf (33.6MB)
    char* ws = (char*)d_ws;
    unsigned short* W1bf = (unsigned short*)ws;
    unsigned short* W2bf = W1bf + (size_t)Kd * M;
    unsigned short* Hbf  = W2bf + (size_t)M * Kd;
    unsigned short* Xbf  = Hbf + (size_t)B * Kd;
    float*          Hf   = (float*)(Xbf + (size_t)B * M);

    const int nx4 = B * M / 4;        // 8,388,608 float4s
    const int nw4 = Kd * M / 4;       //   262,144 float4s each
    const int nh4 = B * Kd / 4;       // 2,097,152 float4s

    cast_zero<<<4096, 256, 0, stream>>>(X, Xbf, nx4, W1, W1bf, W2, W2bf, nw4,
                                        Hf, nh4);

    gemm1_splitk<<<4 * (B / 128) * (Kd / 128), 256, 0, stream>>>(Xbf, W1bf, Hf);

    combineH<<<2048, 256, 0, stream>>>(Hf, b1, Hbf, nh4);

    gemm2<<<(B / 128) * (M / 128), 256, 0, stream>>>(Hbf, W2bf, b2,
                                                     (float*)d_out);
}

// Round 9
// 132.001 us; speedup vs baseline: 1.7255x; 1.7255x over previous
//
#include <hip/hip_runtime.h>
#include <hip/hip_bf16.h>
#include <stdint.h>

// MLP: hidden = X @ W1^T + b1 ; out = hidden @ W2^T + b2
// X [16384,2048] f32, W1 [512,2048], b1 [512], W2 [2048,512], b2 [2048]
// R12: R11 split-K atomics regressed (134 MB atomic write-through; occupancy
// didn't rise -> grid-limit model suspect). Fresh-eyes on the 2-barrier loop:
// "compute; sync; stage; sync" exposes the FULL staging latency between the
// two barriers with zero intra-block overlap -- gemm2 survives via 5-block
// TLP, gemm1_bf (2 blocks/CU, L3-distant A: 8 MB/XCD footprint > 4 MB L2)
// cannot. Fix = T3 minimum 2-phase, never tested on the bf16 clone:
// double-buffer gemm1_bf, issue stage(t+1 -> buf^1) BEFORE compute(buf),
// ONE __syncthreads per step -> loads overlap the whole compute phase.
// cast pass, gemm2, swizzles unchanged (controls). No split-K, no atomics.

typedef short bf16x8 __attribute__((ext_vector_type(8)));
typedef float f32x4 __attribute__((ext_vector_type(4)));

static __device__ __forceinline__ unsigned short f32_to_bf16_rne(float f) {
    unsigned int u = __float_as_uint(f);
    u += 0x7fffu + ((u >> 16) & 1u);
    return (unsigned short)(u >> 16);
}

// one kernel casts X, W1, W2 (f32 -> bf16), grid-stride over float4s
__global__ void cast_bf16_all(const float* __restrict__ x,
                              unsigned short* __restrict__ xo, int nx4,
                              const float* __restrict__ w1,
                              unsigned short* __restrict__ w1o,
                              const float* __restrict__ w2,
                              unsigned short* __restrict__ w2o, int nw4) {
    const int total = nx4 + 2 * nw4;
    const int stride = gridDim.x * blockDim.x;
    for (int i = blockIdx.x * blockDim.x + threadIdx.x; i < total; i += stride) {
        const float* in;
        unsigned short* out;
        int j;
        if (i < nx4) {
            in = x; out = xo; j = i;
        } else if (i < nx4 + nw4) {
            in = w1; out = w1o; j = i - nx4;
        } else {
            in = w2; out = w2o; j = i - nx4 - nw4;
        }
        float4 v = ((const float4*)in)[j];
        ushort4 o;
        o.x = f32_to_bf16_rne(v.x);
        o.y = f32_to_bf16_rne(v.y);
        o.z = f32_to_bf16_rne(v.z);
        o.w = f32_to_bf16_rne(v.w);
        ((ushort4*)out)[j] = o;
    }
}

#define GLOAD_LDS16(gsrc, ldst)                                              \
    __builtin_amdgcn_global_load_lds(                                        \
        (const __attribute__((address_space(1))) void*)(gsrc),               \
        (__attribute__((address_space(3))) void*)(ldst), 16, 0, 0)

// ---------------------------------------------------------------------------
// GEMM1 (bf16): H[16384][512] bf16 = Xbf[16384][2048] @ W1bf[512][2048]^T + b1
// 128x128 tile, 256 thr (2x2 waves of 64x64), BK=64, DOUBLE-buffered 64 KB.
// K=2048 -> NSTEP=32. grid = 512 blocks, chunked XCD swizzle (q=64; the 4
// col-panels sharing an A-panel are consecutive -> same-XCD L2 dedupe).
// T3 2-phase: stage(t+1 -> buf^1) issued BEFORE compute(buf); one
// __syncthreads per step (its vmcnt(0) waits loads that had the whole
// compute phase to land).
// ---------------------------------------------------------------------------
__global__ __launch_bounds__(256)
void gemm1_bf(const unsigned short* __restrict__ A,
              const unsigned short* __restrict__ Bt,
              const float* __restrict__ bias,
              unsigned short* __restrict__ H) {
    constexpr int N = 512, Kd = 2048, BK = 64, NSTEP = Kd / BK;  // 32 steps

    __shared__ __align__(16) unsigned short ldsA[2][128 * BK];  // 2 x 16 KB
    __shared__ __align__(16) unsigned short ldsB[2][128 * BK];  // 2 x 16 KB

    const int tid  = threadIdx.x;
    const int lane = tid & 63;
    const int wid  = tid >> 6;
    const int wr   = wid >> 1;
    const int wc   = wid & 1;

    const int bid = blockIdx.x;
    const int swz = ((bid & 7) << 6) + (bid >> 3);   // nwg=512, q=64
    const int bm  = swz >> 2;            // row-panel's 4 col-blocks adjacent
    const int bn  = swz & 3;
    const int brow = bm << 7;
    const int bcol = bn << 7;

    const int lrow = lane & 15;
    const int ku   = lane >> 4;
    const int rx   = lrow & 7;

    const int srow = tid >> 3;
    const int sgu  = (tid & 7) ^ (srow & 7);

    f32x4 acc[4][4] = {};

    auto stage = [&](int k0, int pb) {
#pragma unroll
        for (int i = 0; i < 4; ++i) {
            const int row = i * 32 + srow;
            const char* sa =
                (const char*)(A + (size_t)(brow + row) * Kd + k0) + (sgu << 4);
            const char* sb =
                (const char*)(Bt + (size_t)(bcol + row) * Kd + k0) + (sgu << 4);
            GLOAD_LDS16(sa, (char*)ldsA[pb] + i * 4096 + tid * 16);
            GLOAD_LDS16(sb, (char*)ldsB[pb] + i * 4096 + tid * 16);
        }
    };
    auto compute = [&](int pb) {
#pragma unroll
        for (int kk = 0; kk < 2; ++kk) {
            const int un = ((ku + (kk << 2)) ^ rx) << 4;
            bf16x8 a[4], b[4];
#pragma unroll
            for (int m = 0; m < 4; ++m)
                a[m] = *(const bf16x8*)((const char*)ldsA[pb] +
                       ((wr << 6) + (m << 4) + lrow) * 128 + un);
#pragma unroll
            for (int n = 0; n < 4; ++n)
                b[n] = *(const bf16x8*)((const char*)ldsB[pb] +
                       ((wc << 6) + (n << 4) + lrow) * 128 + un);
#pragma unroll
            for (int m = 0; m < 4; ++m)
#pragma unroll
                for (int n = 0; n < 4; ++n)
                    acc[m][n] = __builtin_amdgcn_mfma_f32_16x16x32_bf16(
                        a[m], b[n], acc[m][n], 0, 0, 0);
        }
    };

    // prologue: tile 0 -> buf0
    stage(0, 0);
    __syncthreads();

#pragma unroll 1
    for (int t = 0; t < NSTEP; ++t) {
        if (t + 1 < NSTEP) stage((t + 1) * BK, (t + 1) & 1);  // issue-first
        compute(t & 1);
        __syncthreads();   // drains stage(t+1) (overlapped by compute);
                           // also: all waves done reading buf t before t+2
                           // overwrites it next iteration
    }

    // epilogue: C/D layout col = lane&15, row = (lane>>4)*4 + j  [m89]
    const int r0 = (lane >> 4) << 2;
#pragma unroll
    for (int n = 0; n < 4; ++n) {
        const int col = bcol + (wc << 6) + (n << 4) + lrow;
        const float bb = bias[col];
#pragma unroll
        for (int m = 0; m < 4; ++m)
#pragma unroll
            for (int j = 0; j < 4; ++j) {
                const int row = brow + (wr << 6) + (m << 4) + r0 + j;
                H[(size_t)row * N + col] = f32_to_bf16_rne(acc[m][n][j] + bb);
            }
    }
}

// ---------------------------------------------------------------------------
// GEMM2: out[16384][2048] f32 = Hbf[16384][512] @ W2bf[2048][512]^T + b2
// 128x128 tile, 256 thr, BK=64, single-buffered 32 KB -> 5 blocks/CU.
// grid = 128*16 = 2048 blocks, chunked XCD swizzle (q=256). (unchanged)
// ---------------------------------------------------------------------------
__global__ __launch_bounds__(256)
void gemm2(const unsigned short* __restrict__ A,
           const unsigned short* __restrict__ Bt,
           const float* __restrict__ bias,
           float* __restrict__ C) {
    constexpr int N = 2048, Kd = 512, BK = 64, NSTEP = Kd / BK;  // 8 steps

    __shared__ __align__(16) unsigned short ldsA[128 * BK];  // 16 KB
    __shared__ __align__(16) unsigned short ldsB[128 * BK];  // 16 KB

    const int tid  = threadIdx.x;
    const int lane = tid & 63;
    const int wid  = tid >> 6;
    const int wr   = wid >> 1;
    const int wc   = wid & 1;

    const int bid = blockIdx.x;
    const int swz = ((bid & 7) << 8) + (bid >> 3);   // nwg=2048, q=256
    const int bn  = swz & 15;
    const int bm  = swz >> 4;
    const int brow = bm << 7;
    const int bcol = bn << 7;

    const int lrow = lane & 15;
    const int ku   = lane >> 4;
    const int rx   = lrow & 7;

    const int srow = tid >> 3;
    const int sgu  = (tid & 7) ^ (srow & 7);

    f32x4 acc[4][4] = {};

    auto stage = [&](int k0) {
#pragma unroll
        for (int i = 0; i < 4; ++i) {
            const int row = i * 32 + srow;
            const char* sa =
                (const char*)(A + (size_t)(brow + row) * Kd + k0) + (sgu << 4);
            const char* sb =
                (const char*)(Bt + (size_t)(bcol + row) * Kd + k0) + (sgu << 4);
            GLOAD_LDS16(sa, (char*)ldsA + i * 4096 + tid * 16);
            GLOAD_LDS16(sb, (char*)ldsB + i * 4096 + tid * 16);
        }
    };
    auto compute = [&]() {
#pragma unroll
        for (int kk = 0; kk < 2; ++kk) {
            const int un = ((ku + (kk << 2)) ^ rx) << 4;
            bf16x8 a[4], b[4];
#pragma unroll
            for (int m = 0; m < 4; ++m)
                a[m] = *(const bf16x8*)((const char*)ldsA +
                       ((wr << 6) + (m << 4) + lrow) * 128 + un);
#pragma unroll
            for (int n = 0; n < 4; ++n)
                b[n] = *(const bf16x8*)((const char*)ldsB +
                       ((wc << 6) + (n << 4) + lrow) * 128 + un);
#pragma unroll
            for (int m = 0; m < 4; ++m)
#pragma unroll
                for (int n = 0; n < 4; ++n)
                    acc[m][n] = __builtin_amdgcn_mfma_f32_16x16x32_bf16(
                        a[m], b[n], acc[m][n], 0, 0, 0);
        }
    };

    stage(0);
    __syncthreads();

    for (int t = 0; t < NSTEP; ++t) {
        compute();
        if (t + 1 < NSTEP) {
            __syncthreads();
            stage((t + 1) * BK);
            __syncthreads();
        }
    }

    const int r0 = (lane >> 4) << 2;
#pragma unroll
    for (int n = 0; n < 4; ++n) {
        const int col = bcol + (wc << 6) + (n << 4) + lrow;
        const float bb = bias[col];
#pragma unroll
        for (int m = 0; m < 4; ++m)
#pragma unroll
            for (int j = 0; j < 4; ++j) {
                const int row = brow + (wr << 6) + (m << 4) + r0 + j;
                C[(size_t)row * N + col] = acc[m][n][j] + bb;
            }
    }
}

extern "C" void kernel_launch(void* const* d_in, const int* in_sizes, int n_in,
                              void* d_out, int out_size, void* d_ws, size_t ws_size,
                              hipStream_t stream) {
    const float* X  = (const float*)d_in[0];   // [16384][2048]
    const float* W1 = (const float*)d_in[1];   // [512][2048]
    const float* b1 = (const float*)d_in[2];   // [512]
    const float* W2 = (const float*)d_in[3];   // [2048][512]
    const float* b2 = (const float*)d_in[4];   // [2048]

    const int B = 16384, M = 2048, Kd = 512;

    // workspace: W1bf (2MB), W2bf (2MB), Hbf (16.8MB), Xbf (64MB)
    char* ws = (char*)d_ws;
    unsigned short* W1bf = (unsigned short*)ws;
    unsigned short* W2bf = W1bf + (size_t)Kd * M;
    unsigned short* Hbf  = W2bf + (size_t)M * Kd;
    unsigned short* Xbf  = Hbf + (size_t)B * Kd;

    const int nx4 = B * M / 4;        // 8,388,608 float4s
    const int nw4 = Kd * M / 4;       //   262,144 float4s each

    cast_bf16_all<<<4096, 256, 0, stream>>>(X, Xbf, nx4, W1, W1bf, W2, W2bf,
                                            nw4);

    gemm1_bf<<<(B / 128) * (Kd / 128), 256, 0, stream>>>(Xbf, W1bf, b1, Hbf);
    gemm2<<<(B / 128) * (M / 128), 256, 0, stream>>>(Hbf, W2bf, b2,
                                                     (float*)d_out);
}